// Round 8
// baseline (516.990 us; speedup 1.0000x reference)
//
#include <hip/hip_runtime.h>
#include <stdint.h>

#define NCLASS 41
#define TLEN   1024
#define NBATCH 1024
// per-batch backpointer stride: (TLEN-1)*NCLASS = 41943, round to mult of 8
#define BP_STRIDE 41944
#define NTRANS (NCLASS * NCLASS)
#define NEGINF (-3.0e38f)

// Full-wave max + broadcast via DPP (row_shr 1/2/4/8, row_bcast 15/31).
__device__ __forceinline__ float wave_max_bcast(float x) {
    int xi = __float_as_int(x);
    int t;
    t = __builtin_amdgcn_update_dpp(xi, xi, 0x111, 0xf, 0xf, false);  // row_shr:1
    x = fmaxf(x, __int_as_float(t)); xi = __float_as_int(x);
    t = __builtin_amdgcn_update_dpp(xi, xi, 0x112, 0xf, 0xf, false);  // row_shr:2
    x = fmaxf(x, __int_as_float(t)); xi = __float_as_int(x);
    t = __builtin_amdgcn_update_dpp(xi, xi, 0x114, 0xf, 0xf, false);  // row_shr:4
    x = fmaxf(x, __int_as_float(t)); xi = __float_as_int(x);
    t = __builtin_amdgcn_update_dpp(xi, xi, 0x118, 0xf, 0xf, false);  // row_shr:8
    x = fmaxf(x, __int_as_float(t)); xi = __float_as_int(x);
    t = __builtin_amdgcn_update_dpp(xi, xi, 0x142, 0xf, 0xf, false);  // row_bcast:15
    x = fmaxf(x, __int_as_float(t)); xi = __float_as_int(x);
    t = __builtin_amdgcn_update_dpp(xi, xi, 0x143, 0xf, 0xf, false);  // row_bcast:31
    x = fmaxf(x, __int_as_float(t));
    return __int_as_float(__builtin_amdgcn_readlane(__float_as_int(x), 63));
}

#define RDLANE(v, l) __int_as_float(__builtin_amdgcn_readlane(__float_as_int(v), (l)))

// ---------------------------------------------------------------------------
// Kernel A: Viterbi forward. Lagged threshold + EMISSION-PREDICTED prefetch.
//
// thr_{t+1} = M_{t-1} + E_t + (Dmin - D - eps): valid lower bound of
// M_t - D - margin  =>  me = ballot(score_t >= thr) is a SUPERSET of all
// possible argmax winners (proven round 7, bit-exact pass).
// Candidates further satisfy e_t[i] >= E_t - 2D - eps'  (score_t[i] <=
// M_{t-1} + Dmax + e_t[i]), so P = first-4 of {i : em_t[i] >= E_t - WP}
// covers me with high probability AND depends only on emissions -> its
// ballot, readlanes of T-rows (4x ds_read) and mask4 are issued ONE STEP
// EARLY, fully off the critical chain. On-chain per step: ballot ->
// readlane x4 -> add x4 -> masked 4-way merge (ascending index, strict >,
// NEGINF for non-members: exact first-index argmax) -> +em.
// Fail (me has a bit outside mask4, rare): full serial recompute over me.
// ---------------------------------------------------------------------------
__global__ __launch_bounds__(64, 1) void crf_forward(
    const float* __restrict__ x,        // [B, T, C]
    const float* __restrict__ start_t,  // [C]
    const float* __restrict__ end_t,    // [C]
    const float* __restrict__ trans,    // [C, C]
    uint8_t* __restrict__ bp,           // [B, BP_STRIDE]
    int* __restrict__ out)              // [B, T]
{
    __shared__ float tl[NTRANS + 32];

    const int b = blockIdx.x;
    const int j = threadIdx.x;
    const bool act = (j < NCLASS);
    const int jc = act ? j : (NCLASS - 1);

    // Stage trans into LDS; D = max - min (exact, from data)
    float mx = NEGINF, mn = 3.0e38f;
    for (int k = j; k < NTRANS; k += 64) {
        float v = trans[k];
        tl[k] = v;
        mx = fmaxf(mx, v);
        mn = fminf(mn, v);
    }
    __syncthreads();
    const float Dmax = wave_max_bcast(mx);
    const float Dmin = -wave_max_bcast(-mn);
    const float D  = Dmax - Dmin;
    const float Cc = Dmin - D - 2.0e-3f;     // lagged-threshold constant
    const float WP = 2.0f * D + 4.0e-3f;     // prediction window (covers me)

    const float* xb = x + (size_t)b * TLEN * NCLASS;
    uint8_t* bpb = bp + (size_t)b * BP_STRIDE;

    float score = act ? (start_t[j] + xb[j]) : NEGINF;

    // Generation state (A/B ping-pong): predicted indices/rows/mask/thr.
    float tpA0, tpA1, tpA2, tpA3, thrA; int pA0, pA1, pA2, pA3;
    unsigned long long mkA;
    float tpB0, tpB1, tpB2, tpB3, thrB; int pB0, pB1, pB2, pB3;
    unsigned long long mkB;

    // Fill generation G's prediction from mask P_ and threshold thv.
#define FILLGEN(G, P_, thv) do {                                              \
        unsigned long long Pr_ = (P_);                                        \
        int q0 = __ffsll(Pr_) - 1;            Pr_ &= Pr_ - 1;                 \
        int q1 = Pr_ ? __ffsll(Pr_) - 1 : q0; Pr_ &= Pr_ - 1;                 \
        int q2 = Pr_ ? __ffsll(Pr_) - 1 : q1; Pr_ &= Pr_ - 1;                 \
        int q3 = Pr_ ? __ffsll(Pr_) - 1 : q2;                                 \
        p##G##0 = q0; p##G##1 = q1; p##G##2 = q2; p##G##3 = q3;               \
        mk##G = (1ull << q0) | (1ull << q1) | (1ull << q2) | (1ull << q3);    \
        thr##G = (thv);                                                       \
        tp##G##0 = tl[q0 * NCLASS + jc];                                      \
        tp##G##1 = tl[q1 * NCLASS + jc];                                      \
        tp##G##2 = tl[q2 * NCLASS + jc];                                      \
        tp##G##3 = tl[q3 * NCLASS + jc];                                      \
    } while (0)

    // Off-chain prep for the NEXT step: emission trees + predicted prefetch.
    // Must run while `score` still holds score_{t-1} (before EXEC's update).
#define PREP(G, emv) do {                                                     \
        float E_ = wave_max_bcast(emv);                                       \
        float M_ = wave_max_bcast(score);                                     \
        unsigned long long P_ = __ballot((emv) >= E_ - WP);                   \
        FILLGEN(G, P_, M_ + E_ + Cc);                                         \
    } while (0)

    // On-chain step execution using generation G's prefetched state.
#define EXEC(G, emv, t) do {                                                  \
        unsigned long long me = __ballot(score >= thr##G);                    \
        unsigned long long extra = me & ~mk##G;                               \
        float s0_ = RDLANE(score, p##G##0);                                   \
        float s1_ = RDLANE(score, p##G##1);                                   \
        float s2_ = RDLANE(score, p##G##2);                                   \
        float s3_ = RDLANE(score, p##G##3);                                   \
        float v0_ = ((me >> p##G##0) & 1) ? s0_ + tp##G##0 : NEGINF;          \
        float v1_ = ((me >> p##G##1) & 1) ? s1_ + tp##G##1 : NEGINF;          \
        float v2_ = ((me >> p##G##2) & 1) ? s2_ + tp##G##2 : NEGINF;          \
        float v3_ = ((me >> p##G##3) & 1) ? s3_ + tp##G##3 : NEGINF;          \
        float best = v0_; int bidx = p##G##0;                                 \
        if (v1_ > best) { best = v1_; bidx = p##G##1; }                       \
        if (v2_ > best) { best = v2_; bidx = p##G##2; }                       \
        if (v3_ > best) { best = v3_; bidx = p##G##3; }                       \
        if (extra) { /* rare: exact serial recompute over full me */          \
            best = NEGINF; bidx = 0;                                          \
            unsigned long long mm = me;                                       \
            while (mm) {                                                      \
                int ic = __ffsll(mm) - 1; mm &= mm - 1;                       \
                float sc = RDLANE(score, ic);                                 \
                float vc = sc + tl[ic * NCLASS + jc];                         \
                if (vc > best) { best = vc; bidx = ic; }                      \
            }                                                                 \
        }                                                                     \
        if (act) bpb[(size_t)((t) - 1) * NCLASS + j] = (uint8_t)bidx;         \
        score = best + (emv);                                                 \
    } while (0)

    // ---- prologue: exact threshold + exact prediction for step 1 ----
    {
        float M0 = wave_max_bcast(score);
        float th1 = M0 - D - 2.0e-3f;
        unsigned long long P1 = __ballot(score >= th1);
        FILLGEN(A, P1, th1);
    }

    // Rolling 4-deep emission prefetch (rows t=1..4)
    float e0 = xb[1 * NCLASS + jc];
    float e1 = xb[2 * NCLASS + jc];
    float e2 = xb[3 * NCLASS + jc];
    float e3 = xb[4 * NCLASS + jc];

    int t0 = 1;
    for (; t0 + 3 <= TLEN - 4; t0 += 4) {  // steps 1..1020
        int r0 = t0 + 4, r1 = t0 + 5, r2 = t0 + 6, r3 = t0 + 7;
        r0 = r0 > TLEN - 1 ? TLEN - 1 : r0;
        r1 = r1 > TLEN - 1 ? TLEN - 1 : r1;
        r2 = r2 > TLEN - 1 ? TLEN - 1 : r2;
        r3 = r3 > TLEN - 1 ? TLEN - 1 : r3;
        {
            float em = act ? e0 : NEGINF;
            PREP(B, em);              // thr/prefetch for step t0+1
            EXEC(A, em, t0 + 0);
            e0 = xb[(size_t)r0 * NCLASS + jc];
        }
        {
            float em = act ? e1 : NEGINF;
            PREP(A, em);
            EXEC(B, em, t0 + 1);
            e1 = xb[(size_t)r1 * NCLASS + jc];
        }
        {
            float em = act ? e2 : NEGINF;
            PREP(B, em);
            EXEC(A, em, t0 + 2);
            e2 = xb[(size_t)r2 * NCLASS + jc];
        }
        {
            float em = act ? e3 : NEGINF;
            PREP(A, em);
            EXEC(B, em, t0 + 3);
            e3 = xb[(size_t)r3 * NCLASS + jc];
        }
    }
    // Tail: steps 1021 (A), 1022 (B), 1023 (A)
    {
        float em = act ? e0 : NEGINF;
        PREP(B, em);
        EXEC(A, em, TLEN - 3);
    }
    {
        float em = act ? e1 : NEGINF;
        PREP(A, em);
        EXEC(B, em, TLEN - 2);
    }
    {
        float em = act ? e2 : NEGINF;
        EXEC(A, em, TLEN - 1);
    }

    // Final: add end transitions, argmax over lanes (first-index on tie)
    float fs = act ? (score + end_t[j]) : NEGINF;
    int idx = j;
#pragma unroll
    for (int off = 32; off >= 1; off >>= 1) {
        float ov = __shfl_xor(fs, off);
        int oi = __shfl_xor(idx, off);
        if (ov > fs || (ov == fs && oi < idx)) { fs = ov; idx = oi; }
    }
    if (j == 0) out[(size_t)b * TLEN + (TLEN - 1)] = idx;

#undef FILLGEN
#undef PREP
#undef EXEC
}

// ---------------------------------------------------------------------------
// Kernel B: backtracking (unchanged; measured cheap).
// ---------------------------------------------------------------------------
__global__ __launch_bounds__(1024) void crf_backtrack(
    const uint8_t* __restrict__ bp,
    int* __restrict__ out)
{
    __shared__ uint8_t bpl[BP_STRIDE];     // 41944 B
    __shared__ int maps[16][NCLASS];       // chunk boundary maps
    __shared__ int entry[16];              // true tag at each chunk end

    const int b = blockIdx.x;
    const int tid = threadIdx.x;
    const int w = tid >> 6;
    const int lane = tid & 63;

    {
        const uint32_t* src = (const uint32_t*)(bp + (size_t)b * BP_STRIDE);
        uint32_t* dst = (uint32_t*)bpl;
        for (int i = tid; i < BP_STRIDE / 4; i += 1024) dst[i] = src[i];
    }
    __syncthreads();

    const int cs = w * 64;
    const int ce = min(cs + 64, TLEN - 1);  // last chunk: 63 columns
    const int L = ce - cs;

    // Phase 1: hypothesis walk for all 41 entering tags (lane = hypothesis)
    {
        int xx = (lane < NCLASS) ? lane : 0;
        for (int t = ce; t > cs; --t)
            xx = bpl[(t - 1) * NCLASS + xx];
        if (lane < NCLASS) maps[w][lane] = xx;
    }
    __syncthreads();

    // Stitch chunk boundaries serially on one thread
    if (tid == 0) {
        int cur = out[(size_t)b * TLEN + (TLEN - 1)];  // tag @ T-1 from kernel A
        for (int ww = 15; ww >= 0; --ww) {
            entry[ww] = cur;
            cur = maps[ww][cur];
        }
    }
    __syncthreads();

    // Phase 2: replay with true entering tag; lane l captures step l's tag
    {
        int xx = entry[w];
        int cap = 0;
        for (int k = 0; k < L; ++k) {
            xx = bpl[(ce - 1 - k) * NCLASS + xx];
            if (k == lane) cap = xx;
        }
        if (lane < L) out[(size_t)b * TLEN + (ce - 1 - lane)] = cap;
    }
}

// ---------------------------------------------------------------------------
extern "C" void kernel_launch(void* const* d_in, const int* in_sizes, int n_in,
                              void* d_out, int out_size, void* d_ws, size_t ws_size,
                              hipStream_t stream) {
    const float* x       = (const float*)d_in[0];
    const float* start_t = (const float*)d_in[1];
    const float* end_t   = (const float*)d_in[2];
    const float* trans   = (const float*)d_in[3];
    int* out = (int*)d_out;
    uint8_t* bp = (uint8_t*)d_ws;  // needs NBATCH * BP_STRIDE = ~42.9 MB

    crf_forward<<<NBATCH, 64, 0, stream>>>(x, start_t, end_t, trans, bp, out);
    crf_backtrack<<<NBATCH, 1024, 0, stream>>>(bp, out);
}

// Round 9
// 432.740 us; speedup vs baseline: 1.1947x; 1.1947x over previous
//
#include <hip/hip_runtime.h>
#include <stdint.h>

#define NCLASS 41
#define TLEN   1024
#define NBATCH 1024
// per-batch backpointer stride: (TLEN-1)*NCLASS = 41943, round to mult of 8
#define BP_STRIDE 41944
#define NTRANS (NCLASS * NCLASS)
#define NEGINF (-3.0e38f)
#define EPS    2.0e-3f

// Full-wave max + broadcast via DPP (row_shr 1/2/4/8, row_bcast 15/31).
__device__ __forceinline__ float wave_max_bcast(float x) {
    int xi = __float_as_int(x);
    int t;
    t = __builtin_amdgcn_update_dpp(xi, xi, 0x111, 0xf, 0xf, false);  // row_shr:1
    x = fmaxf(x, __int_as_float(t)); xi = __float_as_int(x);
    t = __builtin_amdgcn_update_dpp(xi, xi, 0x112, 0xf, 0xf, false);  // row_shr:2
    x = fmaxf(x, __int_as_float(t)); xi = __float_as_int(x);
    t = __builtin_amdgcn_update_dpp(xi, xi, 0x114, 0xf, 0xf, false);  // row_shr:4
    x = fmaxf(x, __int_as_float(t)); xi = __float_as_int(x);
    t = __builtin_amdgcn_update_dpp(xi, xi, 0x118, 0xf, 0xf, false);  // row_shr:8
    x = fmaxf(x, __int_as_float(t)); xi = __float_as_int(x);
    t = __builtin_amdgcn_update_dpp(xi, xi, 0x142, 0xf, 0xf, false);  // row_bcast:15
    x = fmaxf(x, __int_as_float(t)); xi = __float_as_int(x);
    t = __builtin_amdgcn_update_dpp(xi, xi, 0x143, 0xf, 0xf, false);  // row_bcast:31
    x = fmaxf(x, __int_as_float(t));
    return __int_as_float(__builtin_amdgcn_readlane(__float_as_int(x), 63));
}

#define RDLANE(v, l) __int_as_float(__builtin_amdgcn_readlane(__float_as_int(v), (l)))

// ---------------------------------------------------------------------------
// Kernel A: Viterbi forward. Lagged threshold (trees off-chain) + 4-wide
// straight-line processing of the ACTUAL ballot.
//
// thr_{t+1} = M_{t-1} + E_t + (Dmin - D - EPS) <= M_t - D - eps' =>
// me = ballot(score_t >= thr) is a superset of all possible argmax winners
// (derivation round 7; bit-exact pass). Candidates peeled from BOTH ends of
// me: i1 < i2 <= i3 < i4 ascending (dups when |S|<4) -> sequential strict->
// merge preserves first-index argmax under f32 ties. All 4 ds_reads issue
// back-to-back (one shared LDS latency); the lag-1 DPP trees sit in the LDS
// shadow. |S| >= 5 (rare): full serial ascending recompute - exact.
// ---------------------------------------------------------------------------
__global__ __launch_bounds__(64, 1) void crf_forward(
    const float* __restrict__ x,        // [B, T, C]
    const float* __restrict__ start_t,  // [C]
    const float* __restrict__ end_t,    // [C]
    const float* __restrict__ trans,    // [C, C]
    uint8_t* __restrict__ bp,           // [B, BP_STRIDE]
    int* __restrict__ out)              // [B, T]
{
    __shared__ float tl[NTRANS + 32];

    const int b = blockIdx.x;
    const int j = threadIdx.x;
    const bool act = (j < NCLASS);
    const int jc = act ? j : (NCLASS - 1);

    // Stage trans into LDS; D = max - min (exact, from data)
    float mx = NEGINF, mn = 3.0e38f;
    for (int k = j; k < NTRANS; k += 64) {
        float v = trans[k];
        tl[k] = v;
        mx = fmaxf(mx, v);
        mn = fminf(mn, v);
    }
    __syncthreads();
    const float Dmax = wave_max_bcast(mx);
    const float Dmin = -wave_max_bcast(-mn);
    const float D  = Dmax - Dmin;
    const float Cc = Dmin - D - EPS;    // lagged-threshold constant

    const float* xb = x + (size_t)b * TLEN * NCLASS;
    uint8_t* bpb = bp + (size_t)b * BP_STRIDE;

    float score = act ? (start_t[j] + xb[j]) : NEGINF;

    float thrA, thrB;

    // Bootstrap: exact (zero-lag) threshold for step 1.
    thrA = wave_max_bcast(score) - D - EPS;

    // One step: thrCUR = this step's threshold; PREP_CODE computes the
    // lag-1 trees for thrNXT inside the LDS-wait shadow (uses score_{t-1}
    // and this step's emission - both live at that point).
#define STEP_BODY(thrCUR, thrNXT, emv, t, DO_PREP) do {                       \
        unsigned long long me = __ballot(score >= thrCUR);                    \
        int i1 = __ffsll(me) - 1;                                             \
        int i4 = 63 - __clzll(me);                                            \
        unsigned long long m2 = me & ~((1ull << i1) | (1ull << i4));          \
        int i2 = m2 ? __ffsll(m2) - 1 : i1;                                   \
        int i3 = m2 ? 63 - __clzll(m2) : i1;                                  \
        unsigned long long m3 =                                               \
            m2 ? (m2 & ~((1ull << i2) | (1ull << i3))) : 0ull;                \
        float s1 = RDLANE(score, i1);                                         \
        float s4 = RDLANE(score, i4);                                         \
        float s2 = RDLANE(score, i2);                                         \
        float s3 = RDLANE(score, i3);                                         \
        float t1 = tl[i1 * NCLASS + jc];                                      \
        float t4 = tl[i4 * NCLASS + jc];                                      \
        float t2 = tl[i2 * NCLASS + jc];                                      \
        float t3 = tl[i3 * NCLASS + jc];                                      \
        if (DO_PREP) { /* lag-1 trees: fill the LDS-wait shadow */            \
            float E_ = wave_max_bcast(emv);                                   \
            float M_ = wave_max_bcast(score);                                 \
            thrNXT = M_ + E_ + Cc;                                            \
        }                                                                     \
        float v1 = s1 + t1;                                                   \
        float v2 = s2 + t2;                                                   \
        float v3 = s3 + t3;                                                   \
        float v4 = s4 + t4;                                                   \
        float best = v1; int bidx = i1;                                       \
        if (v2 > best) { best = v2; bidx = i2; }                              \
        if (v3 > best) { best = v3; bidx = i3; }                              \
        if (v4 > best) { best = v4; bidx = i4; }                              \
        if (__builtin_expect(m3 != 0, 0)) { /* |S|>=5: exact serial */        \
            best = NEGINF; bidx = 0;                                          \
            unsigned long long mm = me;                                       \
            while (mm) {                                                      \
                int ic = __ffsll(mm) - 1; mm &= mm - 1;                       \
                float sc = RDLANE(score, ic);                                 \
                float vc = sc + tl[ic * NCLASS + jc];                         \
                if (vc > best) { best = vc; bidx = ic; }                      \
            }                                                                 \
        }                                                                     \
        bpb[(size_t)((t) - 1) * NCLASS + jc] = (uint8_t)bidx;                 \
        score = best + (emv);                                                 \
    } while (0)

    // Rolling 4-deep emission prefetch (rows t=1..4)
    float e0 = xb[1 * NCLASS + jc];
    float e1 = xb[2 * NCLASS + jc];
    float e2 = xb[3 * NCLASS + jc];
    float e3 = xb[4 * NCLASS + jc];

    int t0 = 1;
    for (; t0 + 3 <= TLEN - 4; t0 += 4) {  // steps 1..1020
        int r0 = t0 + 4, r1 = t0 + 5, r2 = t0 + 6, r3 = t0 + 7;
        r0 = r0 > TLEN - 1 ? TLEN - 1 : r0;
        r1 = r1 > TLEN - 1 ? TLEN - 1 : r1;
        r2 = r2 > TLEN - 1 ? TLEN - 1 : r2;
        r3 = r3 > TLEN - 1 ? TLEN - 1 : r3;
        {
            float em = act ? e0 : NEGINF;
            STEP_BODY(thrA, thrB, em, t0 + 0, 1);
            e0 = xb[(size_t)r0 * NCLASS + jc];
        }
        {
            float em = act ? e1 : NEGINF;
            STEP_BODY(thrB, thrA, em, t0 + 1, 1);
            e1 = xb[(size_t)r1 * NCLASS + jc];
        }
        {
            float em = act ? e2 : NEGINF;
            STEP_BODY(thrA, thrB, em, t0 + 2, 1);
            e2 = xb[(size_t)r2 * NCLASS + jc];
        }
        {
            float em = act ? e3 : NEGINF;
            STEP_BODY(thrB, thrA, em, t0 + 3, 1);
            e3 = xb[(size_t)r3 * NCLASS + jc];
        }
    }
    // Tail: steps 1021 (A), 1022 (B), 1023 (A; no prep needed)
    {
        float em = act ? e0 : NEGINF;
        STEP_BODY(thrA, thrB, em, TLEN - 3, 1);
    }
    {
        float em = act ? e1 : NEGINF;
        STEP_BODY(thrB, thrA, em, TLEN - 2, 1);
    }
    {
        float em = act ? e2 : NEGINF;
        STEP_BODY(thrA, thrB, em, TLEN - 1, 0);
    }
#undef STEP_BODY

    // Final: add end transitions, argmax over lanes (first-index on tie)
    float fs = act ? (score + end_t[j]) : NEGINF;
    int idx = j;
#pragma unroll
    for (int off = 32; off >= 1; off >>= 1) {
        float ov = __shfl_xor(fs, off);
        int oi = __shfl_xor(idx, off);
        if (ov > fs || (ov == fs && oi < idx)) { fs = ov; idx = oi; }
    }
    if (j == 0) out[(size_t)b * TLEN + (TLEN - 1)] = idx;
}

// ---------------------------------------------------------------------------
// Kernel B: backtracking (unchanged; measured cheap).
// ---------------------------------------------------------------------------
__global__ __launch_bounds__(1024) void crf_backtrack(
    const uint8_t* __restrict__ bp,
    int* __restrict__ out)
{
    __shared__ uint8_t bpl[BP_STRIDE];     // 41944 B
    __shared__ int maps[16][NCLASS];       // chunk boundary maps
    __shared__ int entry[16];              // true tag at each chunk end

    const int b = blockIdx.x;
    const int tid = threadIdx.x;
    const int w = tid >> 6;
    const int lane = tid & 63;

    {
        const uint32_t* src = (const uint32_t*)(bp + (size_t)b * BP_STRIDE);
        uint32_t* dst = (uint32_t*)bpl;
        for (int i = tid; i < BP_STRIDE / 4; i += 1024) dst[i] = src[i];
    }
    __syncthreads();

    const int cs = w * 64;
    const int ce = min(cs + 64, TLEN - 1);  // last chunk: 63 columns
    const int L = ce - cs;

    // Phase 1: hypothesis walk for all 41 entering tags (lane = hypothesis)
    {
        int xx = (lane < NCLASS) ? lane : 0;
        for (int t = ce; t > cs; --t)
            xx = bpl[(t - 1) * NCLASS + xx];
        if (lane < NCLASS) maps[w][lane] = xx;
    }
    __syncthreads();

    // Stitch chunk boundaries serially on one thread
    if (tid == 0) {
        int cur = out[(size_t)b * TLEN + (TLEN - 1)];  // tag @ T-1 from kernel A
        for (int ww = 15; ww >= 0; --ww) {
            entry[ww] = cur;
            cur = maps[ww][cur];
        }
    }
    __syncthreads();

    // Phase 2: replay with true entering tag; lane l captures step l's tag
    {
        int xx = entry[w];
        int cap = 0;
        for (int k = 0; k < L; ++k) {
            xx = bpl[(ce - 1 - k) * NCLASS + xx];
            if (k == lane) cap = xx;
        }
        if (lane < L) out[(size_t)b * TLEN + (ce - 1 - lane)] = cap;
    }
}

// ---------------------------------------------------------------------------
extern "C" void kernel_launch(void* const* d_in, const int* in_sizes, int n_in,
                              void* d_out, int out_size, void* d_ws, size_t ws_size,
                              hipStream_t stream) {
    const float* x       = (const float*)d_in[0];
    const float* start_t = (const float*)d_in[1];
    const float* end_t   = (const float*)d_in[2];
    const float* trans   = (const float*)d_in[3];
    int* out = (int*)d_out;
    uint8_t* bp = (uint8_t*)d_ws;  // needs NBATCH * BP_STRIDE = ~42.9 MB

    crf_forward<<<NBATCH, 64, 0, stream>>>(x, start_t, end_t, trans, bp, out);
    crf_backtrack<<<NBATCH, 1024, 0, stream>>>(bp, out);
}